// Round 12
// baseline (222.113 us; speedup 1.0000x reference)
//
#include <hip/hip_runtime.h>

// Problem constants (match reference module)
#define VNX 360
#define VNY 160
#define VNZ 48
#define VC 4
static constexpr int PLANE = VNZ * VNY * VNX;   // 2,764,800 voxels per batch

typedef unsigned int u32x4 __attribute__((ext_vector_type(4)));
typedef float        f32x4 __attribute__((ext_vector_type(4)));

// ---------------------------------------------------------------------------
// Pass 2: per-point voxelization, first-point-wins via atomicMin(pid).
// Binning: (p - lo) * 5.0f (NOT /0.2f) — matches XLA-CPU fast-math
// reciprocal rewrite; verified bit-exact in round 4.
//
// DIAGNOSTIC ROUND: this kernel is dispatched TWICE. atomicMin is
// idempotent, so the result is bit-identical; the added time in the bench
// equals the steady-state cost of the points pass (attribution for the
// ~50us gap between the traffic model and measured total).
// ---------------------------------------------------------------------------
__global__ void vox_points_kernel(const float4* __restrict__ pts,
                                  const int* __restrict__ bidx,
                                  unsigned int* __restrict__ winner,
                                  int n) {
    int i = blockIdx.x * blockDim.x + threadIdx.x;
    if (i >= n) return;

    float4 p = pts[i];  // x, y, z, power
    int xi = (int)floorf((p.x -  0.0f) * 5.0f);
    int yi = (int)floorf((p.y + 16.0f) * 5.0f);
    int zi = (int)floorf((p.z +  2.0f) * 5.0f);

    if ((unsigned)xi >= VNX || (unsigned)yi >= VNY || (unsigned)zi >= VNZ)
        return;

    int b = bidx[i];
    int flat = ((b * VNZ + zi) * VNY + yi) * VNX + xi;
    atomicMin(&winner[flat], (unsigned int)i);
}

// ---------------------------------------------------------------------------
// Pass 3: gather + transpose to [B, C, Z, Y, X]. R5 form: grid-stride 2048
// blocks, NT winner loads (read-once), NT output stores (R10: cached worse).
// ---------------------------------------------------------------------------
__global__ void vox_gather_kernel(const u32x4* __restrict__ winner4,
                                  const f32x4* __restrict__ feats,
                                  float* __restrict__ out,
                                  unsigned int n, int nvox4) {
    int stride = gridDim.x * blockDim.x;
    const f32x4 zero = { 0.f, 0.f, 0.f, 0.f };

    for (int t = blockIdx.x * blockDim.x + threadIdx.x; t < nvox4; t += stride) {
        u32x4 w = __builtin_nontemporal_load(&winner4[t]);

        f32x4 f0 = (w.x < n) ? feats[w.x] : zero;
        f32x4 f1 = (w.y < n) ? feats[w.y] : zero;
        f32x4 f2 = (w.z < n) ? feats[w.z] : zero;
        f32x4 f3 = (w.w < n) ? feats[w.w] : zero;

        int v = t * 4;                   // 4 consecutive voxels, same batch
        int b = v / PLANE;               // PLANE % 4 == 0
        int r = v - b * PLANE;
        float* base = out + (size_t)b * (VC * (size_t)PLANE) + r;

        f32x4 c0 = { f0.x, f1.x, f2.x, f3.x };
        f32x4 c1 = { f0.y, f1.y, f2.y, f3.y };
        f32x4 c2 = { f0.z, f1.z, f2.z, f3.z };
        f32x4 c3 = { f0.w, f1.w, f2.w, f3.w };
        __builtin_nontemporal_store(c0, (f32x4*)(base + 0 * (size_t)PLANE));
        __builtin_nontemporal_store(c1, (f32x4*)(base + 1 * (size_t)PLANE));
        __builtin_nontemporal_store(c2, (f32x4*)(base + 2 * (size_t)PLANE));
        __builtin_nontemporal_store(c3, (f32x4*)(base + 3 * (size_t)PLANE));
    }
}

// ---------------------------------------------------------------------------
extern "C" void kernel_launch(void* const* d_in, const int* in_sizes, int n_in,
                              void* d_out, int out_size, void* d_ws, size_t ws_size,
                              hipStream_t stream) {
    const float* rdr  = (const float*)d_in[0];   // [N,4] f32
    const int*   bidx = (const int*)d_in[1];     // [N] int32 on device
    int n = in_sizes[1];

    int G  = out_size / VC;                      // 22,118,400 voxels
    int n4 = G / 4;                              // winner uint4 count

    unsigned int* winner = (unsigned int*)d_ws;  // 88.5 MB (ws is ~1.4 GB)

    int block = 256;
    int grid_dense = 2048;                       // grid-stride, 8 blocks/CU
    int grid_pts   = (n + block - 1) / block;

    // Pass 1: sentinel init (rocclr fill)
    hipMemsetAsync(winner, 0xFF, (size_t)G * sizeof(unsigned int), stream);

    // Pass 2: scatter min point-id per voxel — DISPATCHED TWICE (idempotent)
    // to measure t_points as the dur delta vs R11.
    vox_points_kernel<<<grid_pts, block, 0, stream>>>(
        (const float4*)rdr, bidx, winner, n);
    vox_points_kernel<<<grid_pts, block, 0, stream>>>(
        (const float4*)rdr, bidx, winner, n);

    // Pass 3: gather + channel transpose (R5 form)
    vox_gather_kernel<<<grid_dense, block, 0, stream>>>(
        (const u32x4*)winner, (const f32x4*)rdr, (float*)d_out,
        (unsigned int)n, n4);
}

// Round 13
// 192.552 us; speedup vs baseline: 1.1535x; 1.1535x over previous
//
#include <hip/hip_runtime.h>

// Problem constants (match reference module)
#define VNX 360
#define VNY 160
#define VNZ 48
#define VC 4
static constexpr int PLANE = VNZ * VNY * VNX;   // 2,764,800 voxels per batch

typedef unsigned int u32x4 __attribute__((ext_vector_type(4)));
typedef float        f32x4 __attribute__((ext_vector_type(4)));

// ---------------------------------------------------------------------------
// Pass 1: winner[G] = 0xFFFFFFFF sentinel, NON-TEMPORAL stores.
// SINGLE CHANGE vs R11 (which used hipMemsetAsync = cached rocclr fill).
// Theory: cached init leaves lines dirty in per-XCD L2s; every IC-side
// atomicMin then pays a cross-XCD probe/flush. NT stores leave lines clean
// at the coherent point. (R7 tested this bundled with a gather change —
// uninterpretable; this is the clean A/B.)
// ---------------------------------------------------------------------------
__global__ void vox_init_kernel(u32x4* __restrict__ w4, int n4) {
    int stride = gridDim.x * blockDim.x;
    u32x4 s = { ~0u, ~0u, ~0u, ~0u };
    for (int t = blockIdx.x * blockDim.x + threadIdx.x; t < n4; t += stride)
        __builtin_nontemporal_store(s, &w4[t]);
}

// ---------------------------------------------------------------------------
// Pass 2: per-point voxelization, first-point-wins via atomicMin(pid).
// Binning: (p - lo) * 5.0f (NOT /0.2f) — matches XLA-CPU fast-math
// reciprocal rewrite; verified bit-exact in round 4.
// Measured cost (R12 double-dispatch A/B): ~62 us — the optimization target.
// ---------------------------------------------------------------------------
__global__ void vox_points_kernel(const float4* __restrict__ pts,
                                  const int* __restrict__ bidx,
                                  unsigned int* __restrict__ winner,
                                  int n) {
    int i = blockIdx.x * blockDim.x + threadIdx.x;
    if (i >= n) return;

    float4 p = pts[i];  // x, y, z, power
    int xi = (int)floorf((p.x -  0.0f) * 5.0f);
    int yi = (int)floorf((p.y + 16.0f) * 5.0f);
    int zi = (int)floorf((p.z +  2.0f) * 5.0f);

    if ((unsigned)xi >= VNX || (unsigned)yi >= VNY || (unsigned)zi >= VNZ)
        return;

    int b = bidx[i];
    int flat = ((b * VNZ + zi) * VNY + yi) * VNX + xi;
    atomicMin(&winner[flat], (unsigned int)i);
}

// ---------------------------------------------------------------------------
// Pass 3: gather + transpose to [B, C, Z, Y, X]. R5 form (unchanged):
// grid-stride 2048 blocks, NT winner loads, NT output stores (R10: cached
// stores regress).
// ---------------------------------------------------------------------------
__global__ void vox_gather_kernel(const u32x4* __restrict__ winner4,
                                  const f32x4* __restrict__ feats,
                                  float* __restrict__ out,
                                  unsigned int n, int nvox4) {
    int stride = gridDim.x * blockDim.x;
    const f32x4 zero = { 0.f, 0.f, 0.f, 0.f };

    for (int t = blockIdx.x * blockDim.x + threadIdx.x; t < nvox4; t += stride) {
        u32x4 w = __builtin_nontemporal_load(&winner4[t]);

        f32x4 f0 = (w.x < n) ? feats[w.x] : zero;
        f32x4 f1 = (w.y < n) ? feats[w.y] : zero;
        f32x4 f2 = (w.z < n) ? feats[w.z] : zero;
        f32x4 f3 = (w.w < n) ? feats[w.w] : zero;

        int v = t * 4;                   // 4 consecutive voxels, same batch
        int b = v / PLANE;               // PLANE % 4 == 0
        int r = v - b * PLANE;
        float* base = out + (size_t)b * (VC * (size_t)PLANE) + r;

        f32x4 c0 = { f0.x, f1.x, f2.x, f3.x };
        f32x4 c1 = { f0.y, f1.y, f2.y, f3.y };
        f32x4 c2 = { f0.z, f1.z, f2.z, f3.z };
        f32x4 c3 = { f0.w, f1.w, f2.w, f3.w };
        __builtin_nontemporal_store(c0, (f32x4*)(base + 0 * (size_t)PLANE));
        __builtin_nontemporal_store(c1, (f32x4*)(base + 1 * (size_t)PLANE));
        __builtin_nontemporal_store(c2, (f32x4*)(base + 2 * (size_t)PLANE));
        __builtin_nontemporal_store(c3, (f32x4*)(base + 3 * (size_t)PLANE));
    }
}

// ---------------------------------------------------------------------------
extern "C" void kernel_launch(void* const* d_in, const int* in_sizes, int n_in,
                              void* d_out, int out_size, void* d_ws, size_t ws_size,
                              hipStream_t stream) {
    const float* rdr  = (const float*)d_in[0];   // [N,4] f32
    const int*   bidx = (const int*)d_in[1];     // [N] int32 on device
    int n = in_sizes[1];

    int G  = out_size / VC;                      // 22,118,400 voxels
    int n4 = G / 4;                              // winner uint4 count

    unsigned int* winner = (unsigned int*)d_ws;  // 88.5 MB (ws is ~1.4 GB)

    int block = 256;
    int grid_dense = 2048;                       // grid-stride, 8 blocks/CU

    // Pass 1: sentinel init, NT stores (the single experimental variable)
    vox_init_kernel<<<grid_dense, block, 0, stream>>>((u32x4*)winner, n4);

    // Pass 2: scatter min point-id per voxel
    vox_points_kernel<<<(n + block - 1) / block, block, 0, stream>>>(
        (const float4*)rdr, bidx, winner, n);

    // Pass 3: gather + channel transpose (R5 form)
    vox_gather_kernel<<<grid_dense, block, 0, stream>>>(
        (const u32x4*)winner, (const f32x4*)rdr, (float*)d_out,
        (unsigned int)n, n4);
}